// Round 1
// baseline (78.058 us; speedup 1.0000x reference)
//
#include <hip/hip_runtime.h>
#include <math.h>

#define LSEQ 4096
#define NK 512
#define NB 16

__global__ void build_iperm_kernel(const int* __restrict__ perm, int* __restrict__ iperm) {
    int j = threadIdx.x + blockIdx.x * blockDim.x;
    if (j < NK) iperm[perm[j]] = j;
}

template <int KS>
__global__ __launch_bounds__(256) void rocket_group_kernel(
    const float* __restrict__ x,      // [NB, LSEQ]
    const float* __restrict__ w,      // [n, KS]
    const float* __restrict__ bias,   // [n]
    const int*   __restrict__ off,    // [n, KS]
    const int*   __restrict__ lout,   // [n]
    const int*   __restrict__ iperm,  // [NK]
    const int*   __restrict__ Pp,     // scalar P
    int base,
    float* __restrict__ out)          // [NB, 2*NK]
{
    const int li  = blockIdx.x;   // local kernel index within group
    const int b   = blockIdx.y;   // batch
    const int tid = threadIdx.x;
    const int P   = *Pp;

    float wk[KS];
    int   ofk[KS];
#pragma unroll
    for (int k = 0; k < KS; ++k) {
        wk[k]  = w[li * KS + k];
        ofk[k] = off[li * KS + k] - P;  // x-row index = ofk[k] + t
    }
    const float bi = bias[li];
    const int   Lo = lout[li];
    const float* __restrict__ xr = x + b * LSEQ;

    float mx  = -INFINITY;
    int   cnt = 0;
    for (int t = tid; t < Lo; t += 256) {
        float y = bi;
#pragma unroll
        for (int k = 0; k < KS; ++k) {
            int idx = ofk[k] + t;
            float xv = ((unsigned)idx < (unsigned)LSEQ) ? xr[idx] : 0.0f;
            y = fmaf(wk[k], xv, y);
        }
        mx = fmaxf(mx, y);
        cnt += (y > 0.0f) ? 1 : 0;
    }

    // wave64 reduction
#pragma unroll
    for (int o = 32; o > 0; o >>= 1) {
        mx = fmaxf(mx, __shfl_down(mx, o, 64));
        cnt += __shfl_down(cnt, o, 64);
    }

    __shared__ float smx[4];
    __shared__ int   scnt[4];
    const int wid = tid >> 6;
    if ((tid & 63) == 0) { smx[wid] = mx; scnt[wid] = cnt; }
    __syncthreads();

    if (tid == 0) {
        float m = smx[0];
        int   c = scnt[0];
#pragma unroll
        for (int i = 1; i < 4; ++i) { m = fmaxf(m, smx[i]); c += scnt[i]; }
        const int j = iperm[base + li];
        out[b * (2 * NK) + 2 * j]     = m;
        out[b * (2 * NK) + 2 * j + 1] = (float)c / (float)Lo;
    }
}

extern "C" void kernel_launch(void* const* d_in, const int* in_sizes, int n_in,
                              void* d_out, int out_size, void* d_ws, size_t ws_size,
                              hipStream_t stream) {
    // setup_inputs() dict order:
    // 0:x  1:perm  2:P  3:w0 4:b0 5:off0 6:lout0  7:w1 8:b1 9:off1 10:lout1
    // 11:w2 12:b2 13:off2 14:lout2
    const float* x    = (const float*)d_in[0];
    const int*   perm = (const int*)d_in[1];
    const int*   Pp   = (const int*)d_in[2];
    const float* w0   = (const float*)d_in[3];
    const float* b0   = (const float*)d_in[4];
    const int*   off0 = (const int*)d_in[5];
    const int*   l0   = (const int*)d_in[6];
    const float* w1   = (const float*)d_in[7];
    const float* b1   = (const float*)d_in[8];
    const int*   off1 = (const int*)d_in[9];
    const int*   l1   = (const int*)d_in[10];
    const float* w2   = (const float*)d_in[11];
    const float* b2   = (const float*)d_in[12];
    const int*   off2 = (const int*)d_in[13];
    const int*   l2   = (const int*)d_in[14];

    const int n0 = in_sizes[4];   // |b0|
    const int n1 = in_sizes[8];   // |b1|
    const int n2 = in_sizes[12];  // |b2|

    float* out  = (float*)d_out;
    int* iperm  = (int*)d_ws;     // 512 ints

    build_iperm_kernel<<<1, NK, 0, stream>>>(perm, iperm);

    rocket_group_kernel<7><<<dim3(n0, NB), 256, 0, stream>>>(
        x, w0, b0, off0, l0, iperm, Pp, 0, out);
    rocket_group_kernel<9><<<dim3(n1, NB), 256, 0, stream>>>(
        x, w1, b1, off1, l1, iperm, Pp, n0, out);
    rocket_group_kernel<11><<<dim3(n2, NB), 256, 0, stream>>>(
        x, w2, b2, off2, l2, iperm, Pp, n0 + n1, out);
}

// Round 2
// 61.203 us; speedup vs baseline: 1.2754x; 1.2754x over previous
//
#include <hip/hip_runtime.h>
#include <math.h>

#define LSEQ 4096
#define NK 512
#define NB 16

__global__ void build_iperm_kernel(const int* __restrict__ perm, int* __restrict__ iperm) {
    int j = threadIdx.x + blockIdx.x * blockDim.x;
    if (j < NK) iperm[perm[j]] = j;
}

template <int KS>
__device__ __forceinline__ void rocket_block(
    const float* __restrict__ xr,     // x row for batch b
    const float* __restrict__ w,      // [n, KS]
    const float* __restrict__ bias,   // [n]
    const int*   __restrict__ off,    // [n, KS]
    const int*   __restrict__ lout,   // [n]
    const int*   __restrict__ iperm,  // [NK]
    int P, int base, int li, int b,
    float* __restrict__ out)
{
    const int tid = threadIdx.x;

    float wk[KS];
    int   ofk[KS];
    int   mn = 0x7fffffff, mxo = (int)0x80000000;
#pragma unroll
    for (int k = 0; k < KS; ++k) {
        wk[k]  = w[li * KS + k];
        ofk[k] = off[li * KS + k] - P;   // x-row index = ofk[k] + t
        mn  = min(mn,  ofk[k]);
        mxo = max(mxo, ofk[k]);
    }
    const float bi = bias[li];
    const int   Lo = lout[li];

    // interior range: all taps in [0, LSEQ)
    int t_lo = max(0, -mn);
    t_lo = min(t_lo, Lo);
    int t_hi = min(Lo, LSEQ - mxo);
    if (t_hi < t_lo) t_hi = t_lo;

    float mx  = -INFINITY;
    int   cnt = 0;

    // left edge [0, t_lo): bounds-checked
    for (int t = tid; t < t_lo; t += 256) {
        float y = bi;
#pragma unroll
        for (int k = 0; k < KS; ++k) {
            int idx = ofk[k] + t;
            float xv = ((unsigned)idx < (unsigned)LSEQ) ? xr[idx] : 0.0f;
            y = fmaf(wk[k], xv, y);
        }
        mx = fmaxf(mx, y);
        cnt += (y > 0.0f) ? 1 : 0;
    }

    // interior [t_lo, t_hi): no bounds checks, uniform per-k base + shared voffset
    for (int t = t_lo + tid; t < t_hi; t += 256) {
        float y = bi;
#pragma unroll
        for (int k = 0; k < KS; ++k) {
            y = fmaf(wk[k], xr[ofk[k] + t], y);
        }
        mx = fmaxf(mx, y);
        cnt += (y > 0.0f) ? 1 : 0;
    }

    // right edge [t_hi, Lo): bounds-checked
    for (int t = t_hi + tid; t < Lo; t += 256) {
        float y = bi;
#pragma unroll
        for (int k = 0; k < KS; ++k) {
            int idx = ofk[k] + t;
            float xv = ((unsigned)idx < (unsigned)LSEQ) ? xr[idx] : 0.0f;
            y = fmaf(wk[k], xv, y);
        }
        mx = fmaxf(mx, y);
        cnt += (y > 0.0f) ? 1 : 0;
    }

    // wave64 reduction
#pragma unroll
    for (int o = 32; o > 0; o >>= 1) {
        mx = fmaxf(mx, __shfl_down(mx, o, 64));
        cnt += __shfl_down(cnt, o, 64);
    }

    __shared__ float smx[4];
    __shared__ int   scnt[4];
    const int wid = tid >> 6;
    if ((tid & 63) == 0) { smx[wid] = mx; scnt[wid] = cnt; }
    __syncthreads();

    if (tid == 0) {
        float m = smx[0];
        int   c = scnt[0];
#pragma unroll
        for (int i = 1; i < 4; ++i) { m = fmaxf(m, smx[i]); c += scnt[i]; }
        const int j = iperm[base + li];
        out[b * (2 * NK) + 2 * j]     = m;
        out[b * (2 * NK) + 2 * j + 1] = (float)c / (float)Lo;
    }
}

__global__ __launch_bounds__(256) void rocket_fused_kernel(
    const float* __restrict__ x,
    const float* __restrict__ w0, const float* __restrict__ b0,
    const int* __restrict__ off0, const int* __restrict__ l0,
    const float* __restrict__ w1, const float* __restrict__ b1,
    const int* __restrict__ off1, const int* __restrict__ l1,
    const float* __restrict__ w2, const float* __restrict__ b2,
    const int* __restrict__ off2, const int* __restrict__ l2,
    const int* __restrict__ iperm, const int* __restrict__ Pp,
    int n0, int n01,
    float* __restrict__ out)
{
    const int gid = blockIdx.x;       // 0..511 global kernel index (group-ordered)
    const int b   = blockIdx.y;
    const int P   = *Pp;
    const float* xr = x + (size_t)b * LSEQ;

    if (gid < n0) {
        rocket_block<7>(xr, w0, b0, off0, l0, iperm, P, 0, gid, b, out);
    } else if (gid < n01) {
        rocket_block<9>(xr, w1, b1, off1, l1, iperm, P, n0, gid - n0, b, out);
    } else {
        rocket_block<11>(xr, w2, b2, off2, l2, iperm, P, n01, gid - n01, b, out);
    }
}

extern "C" void kernel_launch(void* const* d_in, const int* in_sizes, int n_in,
                              void* d_out, int out_size, void* d_ws, size_t ws_size,
                              hipStream_t stream) {
    const float* x    = (const float*)d_in[0];
    const int*   perm = (const int*)d_in[1];
    const int*   Pp   = (const int*)d_in[2];
    const float* w0   = (const float*)d_in[3];
    const float* b0   = (const float*)d_in[4];
    const int*   off0 = (const int*)d_in[5];
    const int*   l0   = (const int*)d_in[6];
    const float* w1   = (const float*)d_in[7];
    const float* b1   = (const float*)d_in[8];
    const int*   off1 = (const int*)d_in[9];
    const int*   l1   = (const int*)d_in[10];
    const float* w2   = (const float*)d_in[11];
    const float* b2   = (const float*)d_in[12];
    const int*   off2 = (const int*)d_in[13];
    const int*   l2   = (const int*)d_in[14];

    const int n0 = in_sizes[4];
    const int n1 = in_sizes[8];

    float* out = (float*)d_out;
    int* iperm = (int*)d_ws;

    build_iperm_kernel<<<1, NK, 0, stream>>>(perm, iperm);

    rocket_fused_kernel<<<dim3(NK, NB), 256, 0, stream>>>(
        x, w0, b0, off0, l0, w1, b1, off1, l1, w2, b2, off2, l2,
        iperm, Pp, n0, n0 + n1, out);
}